// Round 3
// baseline (171.231 us; speedup 1.0000x reference)
//
#include <hip/hip_runtime.h>
#include <hip/hip_bf16.h>

#define BB 8
#define TT 2048
#define CC 1024
#define HH 64
#define NTRI 528                 // 32*33/2 triangular 64x64 tiles per batch
#define NPB (TT * HH)            // 131072 elems per batch per tensor

typedef unsigned short ushort_t;
typedef __attribute__((ext_vector_type(8))) short bf16x8;
typedef __attribute__((ext_vector_type(4))) float f32x4;

__device__ __forceinline__ float bf2f(ushort_t u) {
    unsigned int x = ((unsigned int)u) << 16;
    return __uint_as_float(x);
}
__device__ __forceinline__ ushort_t f2bf(float f) {
    unsigned int x = __float_as_uint(f);
    unsigned int lsb = (x >> 16) & 1;
    x += 0x7fffu + lsb;   // round-to-nearest-even
    return (ushort_t)(x >> 16);
}

// ---------------------------------------------------------------------------
// Kernel 0: pack weights into MFMA B-fragment records.
// wpack[part(5)][kc(32)][nt(4)][lane(64)][8]; parts: qh,ql,kh,kl,vh.
// record elem j (lane=(quad,l15)): W[c=kc*32+quad*8+j][h=nt*16+l15]
// ---------------------------------------------------------------------------
__global__ __launch_bounds__(256) void wsplit_kernel(
    const float* __restrict__ Wq, const float* __restrict__ Wk,
    const float* __restrict__ Wv, ushort_t* __restrict__ wpack)
{
    int slot = blockIdx.x * 256 + threadIdx.x;   // [0, 40960)
    int rec = slot >> 6, lane = slot & 63;
    int quad = lane >> 4, l15 = lane & 15;
    int part = rec >> 7;
    int r2 = rec & 127;
    int kc = r2 >> 2, nt = r2 & 3;
    const float* W = (part < 2) ? Wq : (part < 4) ? Wk : Wv;
    bool lo = (part < 4) && (part & 1);
    bf16x8 o;
    #pragma unroll
    for (int j = 0; j < 8; j++) {
        int c = kc * 32 + quad * 8 + j;
        float w = W[(size_t)c * HH + nt * 16 + l15];
        ushort_t h = f2bf(w);
        o[j] = (short)(lo ? f2bf(w - bf2f(h)) : h);
    }
    *(bf16x8*)(wpack + (size_t)rec * 512 + lane * 8) = o;
}

// ---------------------------------------------------------------------------
// Kernel 1 (v2): fused q/k/v projection. Block = 16 M rows (one m-tile),
// grid 1024. Wave wid = nt: computes q,k,v for n-tile nt of its 16 rows.
// Double-buffered LDS x staging: ONE barrier per K-step.
// Occupancy cap: 1024 blocks / 256 CU = 4 blocks x 4 waves = 16 waves/CU.
// ---------------------------------------------------------------------------
__global__ __launch_bounds__(256) void proj_mfma(
    const float* __restrict__ x, const ushort_t* __restrict__ wpack,
    ushort_t* __restrict__ qpk, ushort_t* __restrict__ qpl,
    ushort_t* __restrict__ kpk, ushort_t* __restrict__ kpl,
    ushort_t* __restrict__ vpk)
{
    const int tid = threadIdx.x;
    const int lane = tid & 63, wid = tid >> 6;
    const int quad = lane >> 4, l15 = lane & 15;
    const int r0 = blockIdx.x * 16;
    const int nt = wid;                       // wave's n-tile (0..3)

    __shared__ __align__(16) ushort_t xh[2][16][72];   // 4.6 KB
    __shared__ __align__(16) ushort_t xl[2][16][72];   // 4.6 KB
    __shared__ __align__(16) float sC[3][16][72];      // 13.8 KB

    f32x4 acc[3];
    #pragma unroll
    for (int p = 0; p < 3; p++)
        acc[p] = (f32x4){0.f, 0.f, 0.f, 0.f};

    // staging geometry: 256 threads x float4 = one 16x64 f32 tile
    const int srow = tid >> 4, sc4 = (tid & 15) * 4;
    const float* xrow = x + (size_t)(r0 + srow) * CC + sc4;

    // prefetch first tile
    float4 cur = *(const float4*)xrow;

    const size_t lb8 = (size_t)lane * 8;

    for (int bk = 0; bk < 16; bk++) {
        const int buf = bk & 1;
        // convert + stage current tile
        {
            float vv[4] = {cur.x, cur.y, cur.z, cur.w};
            ushort4 h4, l4;
            ushort_t* hp = (ushort_t*)&h4;
            ushort_t* lp = (ushort_t*)&l4;
            #pragma unroll
            for (int j = 0; j < 4; j++) {
                ushort_t h = f2bf(vv[j]);
                hp[j] = h;
                lp[j] = f2bf(vv[j] - bf2f(h));
            }
            *(ushort4*)(&xh[buf][srow][sc4]) = h4;
            *(ushort4*)(&xl[buf][srow][sc4]) = l4;
        }
        __syncthreads();                       // single barrier per K-step
        if (bk < 15)                           // prefetch next (overlaps MFMA)
            cur = *(const float4*)(xrow + (bk + 1) * 64);

        #pragma unroll
        for (int c = 0; c < 2; c++) {
            const int kc = bk * 2 + c;
            bf16x8 aH = *(const bf16x8*)(&xh[buf][l15][c * 32 + quad * 8]);
            bf16x8 aL = *(const bf16x8*)(&xl[buf][l15][c * 32 + quad * 8]);
            bf16x8 bQh = *(const bf16x8*)(wpack + (((size_t)(0 * 32 + kc) * 4 + nt) * 512) + lb8);
            bf16x8 bQl = *(const bf16x8*)(wpack + (((size_t)(1 * 32 + kc) * 4 + nt) * 512) + lb8);
            bf16x8 bKh = *(const bf16x8*)(wpack + (((size_t)(2 * 32 + kc) * 4 + nt) * 512) + lb8);
            bf16x8 bKl = *(const bf16x8*)(wpack + (((size_t)(3 * 32 + kc) * 4 + nt) * 512) + lb8);
            bf16x8 bVh = *(const bf16x8*)(wpack + (((size_t)(4 * 32 + kc) * 4 + nt) * 512) + lb8);
            acc[0] = __builtin_amdgcn_mfma_f32_16x16x32_bf16(aL, bQh, acc[0], 0, 0, 0);
            acc[0] = __builtin_amdgcn_mfma_f32_16x16x32_bf16(aH, bQl, acc[0], 0, 0, 0);
            acc[0] = __builtin_amdgcn_mfma_f32_16x16x32_bf16(aH, bQh, acc[0], 0, 0, 0);
            acc[1] = __builtin_amdgcn_mfma_f32_16x16x32_bf16(aL, bKh, acc[1], 0, 0, 0);
            acc[1] = __builtin_amdgcn_mfma_f32_16x16x32_bf16(aH, bKl, acc[1], 0, 0, 0);
            acc[1] = __builtin_amdgcn_mfma_f32_16x16x32_bf16(aH, bKh, acc[1], 0, 0, 0);
            acc[2] = __builtin_amdgcn_mfma_f32_16x16x32_bf16(aH, bVh, acc[2], 0, 0, 0);
        }
    }

    // write accumulators to sC (wave owns columns nt*16..nt*16+15)
    #pragma unroll
    for (int p = 0; p < 3; p++)
        #pragma unroll
        for (int r = 0; r < 4; r++)
            sC[p][quad * 4 + r][nt * 16 + l15] = acc[p][r];
    __syncthreads();

    const int b = r0 >> 11;
    const int gt = (r0 & 2047) >> 4;   // global 16-row tile index within batch

    // emit q,k packed hi/lo: wave rec = (p, ksR); elem j = C[l15][ksR*32+quad*8+j]
    {
        const int rec = wid;
        const int p = rec >> 1, ksR = rec & 1;
        const size_t dst = (size_t)b * NPB + (((size_t)ksR * 128 + gt) * 64 + lane) * 8;
        const float* src = &sC[p][l15][ksR * 32 + quad * 8];
        f32x4 v0 = *(const f32x4*)src;
        f32x4 v1 = *(const f32x4*)(src + 4);
        bf16x8 h8, l8;
        #pragma unroll
        for (int j = 0; j < 4; j++) {
            ushort_t h = f2bf(v0[j]);
            h8[j] = (short)h;
            l8[j] = (short)f2bf(v0[j] - bf2f(h));
        }
        #pragma unroll
        for (int j = 0; j < 4; j++) {
            ushort_t h = f2bf(v1[j]);
            h8[4 + j] = (short)h;
            l8[4 + j] = (short)f2bf(v1[j] - bf2f(h));
        }
        *(bf16x8*)((p == 0 ? qpk : kpk) + dst) = h8;
        *(bf16x8*)((p == 0 ? qpl : kpl) + dst) = l8;
    }
    // emit v packed (PV B-frag order, unscaled): elem j = v[s=quad*8+j][h=nt*16+l15]
    // This block covers half of the 32-row s-chunk: only quads in our half store.
    {
        const int scL = (r0 & 2047) >> 5;        // 32-row s-chunk
        const int half = (r0 >> 4) & 1;          // which 16-row half we own
        if ((quad >> 1) == half) {
            bf16x8 o;
            #pragma unroll
            for (int j = 0; j < 8; j++)
                o[j] = (short)f2bf(sC[2][(quad & 1) * 8 + j][nt * 16 + l15]);
            *(bf16x8*)(vpk + (size_t)b * NPB + (((size_t)scL * 4 + nt) * 64 + lane) * 8) = o;
        }
    }
}

// ---------------------------------------------------------------------------
// Kernel 2: l[b,s] += column sums of exp(qk^T); stores P = exp(S) bf16 in
// PV-A-fragment-packed triangular tiles. Block 128x128, wave 64x64.
// ---------------------------------------------------------------------------
__global__ __launch_bounds__(256) void colsum_mfma(
    const ushort_t* __restrict__ qpk, const ushort_t* __restrict__ qpl,
    const ushort_t* __restrict__ kpk, const ushort_t* __restrict__ kpl,
    float* __restrict__ lsum, ushort_t* __restrict__ Ppack)
{
    const int tc = blockIdx.x, st = blockIdx.y, b = blockIdx.z;
    if (tc < st) return;
    const int tid = threadIdx.x;
    const int lane = tid & 63, wid = tid >> 6;
    const int quad = lane >> 4, l15 = lane & 15;
    const int wy = wid >> 1, wx = wid & 1;
    const int t_base = tc * 128 + wy * 64;
    const int s_base = st * 128 + wx * 64;
    if (t_base < s_base) return;
    const bool needMask = (t_base == s_base);

    __shared__ __align__(16) ushort_t sT[4][64][72];   // 36.9 KB, wave-private

    const size_t bq = (size_t)b * NPB;
    const size_t lb8 = (size_t)lane * 8;

    // B preload: k fragments (packed layout = A layout)
    bf16x8 bH[4][2], bL[4][2];
    #pragma unroll
    for (int nt = 0; nt < 4; nt++)
        #pragma unroll
        for (int ks = 0; ks < 2; ks++) {
            const size_t off = bq + (((size_t)ks * 128 + (s_base >> 4) + nt) * 64) * 8 + lb8;
            bH[nt][ks] = *(const bf16x8*)(kpk + off);
            bL[nt][ks] = *(const bf16x8*)(kpl + off);
        }

    float cs[4] = {0.f, 0.f, 0.f, 0.f};

    #pragma unroll
    for (int mt = 0; mt < 4; mt++) {
        bf16x8 aH[2], aL[2];
        #pragma unroll
        for (int ks = 0; ks < 2; ks++) {
            const size_t off = bq + (((size_t)ks * 128 + (t_base >> 4) + mt) * 64) * 8 + lb8;
            aH[ks] = *(const bf16x8*)(qpk + off);
            aL[ks] = *(const bf16x8*)(qpl + off);
        }
        f32x4 acc[4];
        #pragma unroll
        for (int nt = 0; nt < 4; nt++)
            acc[nt] = (f32x4){0.f, 0.f, 0.f, 0.f};
        #pragma unroll
        for (int nt = 0; nt < 4; nt++)
            #pragma unroll
            for (int ks = 0; ks < 2; ks++) {
                acc[nt] = __builtin_amdgcn_mfma_f32_16x16x32_bf16(aL[ks], bH[nt][ks], acc[nt], 0, 0, 0);
                acc[nt] = __builtin_amdgcn_mfma_f32_16x16x32_bf16(aH[ks], bL[nt][ks], acc[nt], 0, 0, 0);
                acc[nt] = __builtin_amdgcn_mfma_f32_16x16x32_bf16(aH[ks], bH[nt][ks], acc[nt], 0, 0, 0);
            }
        #pragma unroll
        for (int nt = 0; nt < 4; nt++)
            #pragma unroll
            for (int r = 0; r < 4; r++) {
                float e = __expf(acc[nt][r]);
                if (needMask) {
                    int t = mt * 16 + quad * 4 + r;
                    int s = nt * 16 + l15;
                    if (t < s) e = 0.f;
                }
                cs[nt] += e;
                sT[wid][mt * 16 + quad * 4 + r][nt * 16 + l15] = f2bf(e);
            }
    }

    #pragma unroll
    for (int nt = 0; nt < 4; nt++) {
        float v = cs[nt];
        v += __shfl_xor(v, 16);
        v += __shfl_xor(v, 32);
        if (quad == 0)
            atomicAdd(lsum + (size_t)b * TT + s_base + nt * 16 + l15, v);
    }

    // emit P tile as 8 A-frag records: rec=(mtP,ksP), elem j = P[mtP*16+l15][ksP*32+quad*8+j]
    const int ti = t_base >> 6, si = s_base >> 6;
    ushort_t* tp = Ppack + ((size_t)b * NTRI + (size_t)(ti * (ti + 1) / 2) + si) * 4096;
    #pragma unroll
    for (int rec = 0; rec < 8; rec++) {
        const int mtP = rec >> 1, ksP = rec & 1;
        bf16x8 v8 = *(const bf16x8*)&sT[wid][mtP * 16 + l15][ksP * 32 + quad * 8];
        *(bf16x8*)(tp + (size_t)rec * 512 + lb8) = v8;
    }
}

// ---------------------------------------------------------------------------
// Kernel 2b: scale packed v records by 1/l[s]  (s = sc*32 + quad*8 + j)
// ---------------------------------------------------------------------------
__global__ __launch_bounds__(256) void vscale_kernel(
    const ushort_t* __restrict__ vpk, const float* __restrict__ lsum,
    ushort_t* __restrict__ vps)
{
    size_t slot = (size_t)blockIdx.x * 256 + threadIdx.x;   // 131072 slots
    int lane = (int)(slot & 63);
    int quad = lane >> 4;
    int sc_b = (int)(slot >> 8);          // b*64 + sc
    int b = sc_b >> 6, sc = sc_b & 63;
    bf16x8 in = *(const bf16x8*)(vpk + slot * 8);
    const float* lp = lsum + (size_t)b * TT + sc * 32 + quad * 8;
    float4 l0 = *(const float4*)lp;
    float4 l1 = *(const float4*)(lp + 4);
    float li[8] = {l0.x, l0.y, l0.z, l0.w, l1.x, l1.y, l1.z, l1.w};
    bf16x8 o;
    #pragma unroll
    for (int j = 0; j < 8; j++)
        o[j] = (short)f2bf(bf2f((ushort_t)in[j]) / li[j]);
    *(bf16x8*)(vps + slot * 8) = o;
}

// ---------------------------------------------------------------------------
// Kernel 3: out = P * vs^T from packed fragments. grid (32 pairs, 8 b).
// Block: t-tiles p and 63-p (32 rows each); 4 waves stride s-chunks.
// ---------------------------------------------------------------------------
__global__ __launch_bounds__(256) void attn_pv(
    const ushort_t* __restrict__ Ppack, const ushort_t* __restrict__ vps,
    float* __restrict__ out)
{
    const int p = blockIdx.x, b = blockIdx.y;
    const int tid = threadIdx.x;
    const int lane = tid & 63, wid = tid >> 6;
    const int quad = lane >> 4, l15 = lane & 15;
    const size_t lb8 = (size_t)lane * 8;

    __shared__ __align__(16) float red[4][2048];   // 32 KB

    const ushort_t* vb_ = vps + (size_t)b * NPB;

    #pragma unroll
    for (int half = 0; half < 2; half++) {
        const int tileI = half ? (63 - p) : p;
        const int t0 = tileI * 32;
        const int ti = t0 >> 6, trel16 = (t0 & 63) >> 4;   // 0 or 2
        const size_t triBase = ((size_t)b * NTRI + (size_t)(ti * (ti + 1) / 2)) * 4096;

        f32x4 oacc[2][4];
        #pragma unroll
        for (int mt = 0; mt < 2; mt++)
            #pragma unroll
            for (int nt = 0; nt < 4; nt++)
                oacc[mt][nt] = (f32x4){0.f, 0.f, 0.f, 0.f};

        for (int s0 = wid * 64; s0 <= t0 + 31; s0 += 256) {
            const int si = s0 >> 6;
            const ushort_t* tp = Ppack + triBase + (size_t)si * 4096;
            bf16x8 pa[2][2];
            #pragma unroll
            for (int mt = 0; mt < 2; mt++)
                #pragma unroll
                for (int ks = 0; ks < 2; ks++)
                    pa[mt][ks] = *(const bf16x8*)(tp + (size_t)((trel16 + mt) * 2 + ks) * 512 + lb8);
            #pragma unroll
            for (int ks = 0; ks < 2; ks++)
                #pragma unroll
                for (int nt = 0; nt < 4; nt++) {
                    bf16x8 vb = *(const bf16x8*)(vb_ + (((size_t)(s0 >> 5) + ks) * 4 + nt) * 512 + lb8);
                    #pragma unroll
                    for (int mt = 0; mt < 2; mt++)
                        oacc[mt][nt] = __builtin_amdgcn_mfma_f32_16x16x32_bf16(pa[mt][ks], vb, oacc[mt][nt], 0, 0, 0);
                }
        }

        __syncthreads();
        #pragma unroll
        for (int mt = 0; mt < 2; mt++)
            #pragma unroll
            for (int nt = 0; nt < 4; nt++)
                #pragma unroll
                for (int r = 0; r < 4; r++)
                    red[wid][(mt * 16 + quad * 4 + r) * 64 + nt * 16 + l15] =
                        oacc[mt][nt][r];
        __syncthreads();
        for (int e = tid; e < 2048; e += 256) {
            float s_ = red[0][e] + red[1][e] + red[2][e] + red[3][e];
            out[(size_t)(b * TT + t0 + (e >> 6)) * HH + (e & 63)] = s_;
        }
        __syncthreads();
    }
}

extern "C" void kernel_launch(void* const* d_in, const int* in_sizes, int n_in,
                              void* d_out, int out_size, void* d_ws, size_t ws_size,
                              hipStream_t stream)
{
    const float* x  = (const float*)d_in[0];
    const float* Wq = (const float*)d_in[1];
    const float* Wk = (const float*)d_in[2];
    const float* Wv = (const float*)d_in[3];
    float* out = (float*)d_out;

    const size_t N = (size_t)BB * TT * HH;     // 1,048,576
    ushort_t* qpk = (ushort_t*)d_ws;
    ushort_t* qpl = qpk + N;
    ushort_t* kpk = qpl + N;
    ushort_t* kpl = kpk + N;
    ushort_t* vpk = kpl + N;
    ushort_t* vps = vpk + N;
    float* lsum = (float*)(vps + N);                        // [8][2048]
    ushort_t* wpack = (ushort_t*)(lsum + (size_t)BB * TT);  // 327,680 elems
    ushort_t* Ppack = wpack + (size_t)5 * 32 * 4 * 512;     // 17,301,504 elems

    hipMemsetAsync(lsum, 0, (size_t)BB * TT * sizeof(float), stream);
    wsplit_kernel<<<dim3(160), 256, 0, stream>>>(Wq, Wk, Wv, wpack);
    proj_mfma<<<dim3(1024), 256, 0, stream>>>(x, wpack, qpk, qpl, kpk, kpl, vpk);
    colsum_mfma<<<dim3(16, 16, BB), 256, 0, stream>>>(qpk, qpl, kpk, kpl, lsum, Ppack);
    vscale_kernel<<<dim3(512), 256, 0, stream>>>(vpk, lsum, vps);
    attn_pv<<<dim3(32, BB), 256, 0, stream>>>(Ppack, vps, out);
}

// Round 4
// 159.167 us; speedup vs baseline: 1.0758x; 1.0758x over previous
//
#include <hip/hip_runtime.h>
#include <hip/hip_bf16.h>

#define BB 8
#define TT 2048
#define CC 1024
#define HH 64
#define NTRI 528                 // 32*33/2 triangular 64x64 tiles per batch
#define NPB (TT * HH)            // 131072 elems per batch per tensor

typedef unsigned short ushort_t;
typedef __attribute__((ext_vector_type(8))) short bf16x8;
typedef __attribute__((ext_vector_type(4))) float f32x4;

__device__ __forceinline__ float bf2f(ushort_t u) {
    unsigned int x = ((unsigned int)u) << 16;
    return __uint_as_float(x);
}
__device__ __forceinline__ ushort_t f2bf(float f) {
    unsigned int x = __float_as_uint(f);
    unsigned int lsb = (x >> 16) & 1;
    x += 0x7fffu + lsb;   // round-to-nearest-even
    return (ushort_t)(x >> 16);
}

// ---------------------------------------------------------------------------
// Kernel 0: pack weights into MFMA B-fragment records.
// wpack[part(5)][kc(32)][nt(4)][lane(64)][8]; parts: qh,ql,kh,kl,vh.
// record elem j (lane=(quad,l15)): W[c=kc*32+quad*8+j][h=nt*16+l15]
// ---------------------------------------------------------------------------
__global__ __launch_bounds__(256) void wsplit_kernel(
    const float* __restrict__ Wq, const float* __restrict__ Wk,
    const float* __restrict__ Wv, ushort_t* __restrict__ wpack)
{
    int slot = blockIdx.x * 256 + threadIdx.x;   // [0, 40960)
    int rec = slot >> 6, lane = slot & 63;
    int quad = lane >> 4, l15 = lane & 15;
    int part = rec >> 7;
    int r2 = rec & 127;
    int kc = r2 >> 2, nt = r2 & 3;
    const float* W = (part < 2) ? Wq : (part < 4) ? Wk : Wv;
    bool lo = (part < 4) && (part & 1);
    bf16x8 o;
    #pragma unroll
    for (int j = 0; j < 8; j++) {
        int c = kc * 32 + quad * 8 + j;
        float w = W[(size_t)c * HH + nt * 16 + l15];
        ushort_t h = f2bf(w);
        o[j] = (short)(lo ? f2bf(w - bf2f(h)) : h);
    }
    *(bf16x8*)(wpack + (size_t)rec * 512 + lane * 8) = o;
}

// ---------------------------------------------------------------------------
// Kernel 1 (v3): fused q/k/v projection. Block = 64 M rows, grid 256.
// Wave wid = nt, computes 4 m-subtiles -> 28 MFMAs per 5 wpack loads
// (4x amortization vs v2; wpack L2 traffic 655 MB -> 164 MB).
// Double-buffered LDS x staging, ONE barrier per K-step. ILP over TLP.
// ---------------------------------------------------------------------------
__global__ __launch_bounds__(256) void proj_mfma(
    const float* __restrict__ x, const ushort_t* __restrict__ wpack,
    ushort_t* __restrict__ qpk, ushort_t* __restrict__ qpl,
    ushort_t* __restrict__ kpk, ushort_t* __restrict__ kpl,
    ushort_t* __restrict__ vpk)
{
    const int tid = threadIdx.x;
    const int lane = tid & 63, wid = tid >> 6;
    const int quad = lane >> 4, l15 = lane & 15;
    const int r0 = blockIdx.x * 64;
    const int nt = wid;                       // wave's n-tile (0..3)

    __shared__ __align__(16) ushort_t xh[2][64][72];   // 18.4 KB
    __shared__ __align__(16) ushort_t xl[2][64][72];   // 18.4 KB
    __shared__ __align__(16) float sC[3][64][72];      // 55.3 KB

    f32x4 acc[3][4];
    #pragma unroll
    for (int p = 0; p < 3; p++)
        #pragma unroll
        for (int mt = 0; mt < 4; mt++)
            acc[p][mt] = (f32x4){0.f, 0.f, 0.f, 0.f};

    // staging geometry: 256 threads x 4 float4 = one 64x64 f32 tile
    // slot = tid + i*256 -> row = srow0 + i*16, col4 = (tid&15)*4
    const int srow0 = tid >> 4, sc4 = (tid & 15) * 4;
    const float* xbase = x + (size_t)(r0 + srow0) * CC + sc4;

    float4 cur[4];
    #pragma unroll
    for (int i = 0; i < 4; i++)
        cur[i] = *(const float4*)(xbase + (size_t)i * 16 * CC);

    const size_t lb8 = (size_t)lane * 8;

    for (int bk = 0; bk < 16; bk++) {
        const int buf = bk & 1;
        // convert + stage current tile
        #pragma unroll
        for (int i = 0; i < 4; i++) {
            float vv[4] = {cur[i].x, cur[i].y, cur[i].z, cur[i].w};
            ushort4 h4, l4;
            ushort_t* hp = (ushort_t*)&h4;
            ushort_t* lp = (ushort_t*)&l4;
            #pragma unroll
            for (int j = 0; j < 4; j++) {
                ushort_t h = f2bf(vv[j]);
                hp[j] = h;
                lp[j] = f2bf(vv[j] - bf2f(h));
            }
            *(ushort4*)(&xh[buf][srow0 + i * 16][sc4]) = h4;
            *(ushort4*)(&xl[buf][srow0 + i * 16][sc4]) = l4;
        }
        __syncthreads();                       // single barrier per K-step
        if (bk < 15) {                         // prefetch next (overlaps MFMA)
            #pragma unroll
            for (int i = 0; i < 4; i++)
                cur[i] = *(const float4*)(xbase + (size_t)i * 16 * CC + (bk + 1) * 64);
        }

        #pragma unroll
        for (int c = 0; c < 2; c++) {
            const int kc = bk * 2 + c;
            bf16x8 bQh = *(const bf16x8*)(wpack + (((size_t)(0 * 32 + kc) * 4 + nt) * 512) + lb8);
            bf16x8 bQl = *(const bf16x8*)(wpack + (((size_t)(1 * 32 + kc) * 4 + nt) * 512) + lb8);
            bf16x8 bKh = *(const bf16x8*)(wpack + (((size_t)(2 * 32 + kc) * 4 + nt) * 512) + lb8);
            bf16x8 bKl = *(const bf16x8*)(wpack + (((size_t)(3 * 32 + kc) * 4 + nt) * 512) + lb8);
            bf16x8 bVh = *(const bf16x8*)(wpack + (((size_t)(4 * 32 + kc) * 4 + nt) * 512) + lb8);
            #pragma unroll
            for (int mt = 0; mt < 4; mt++) {
                bf16x8 aH = *(const bf16x8*)(&xh[buf][mt * 16 + l15][c * 32 + quad * 8]);
                bf16x8 aL = *(const bf16x8*)(&xl[buf][mt * 16 + l15][c * 32 + quad * 8]);
                acc[0][mt] = __builtin_amdgcn_mfma_f32_16x16x32_bf16(aL, bQh, acc[0][mt], 0, 0, 0);
                acc[0][mt] = __builtin_amdgcn_mfma_f32_16x16x32_bf16(aH, bQl, acc[0][mt], 0, 0, 0);
                acc[0][mt] = __builtin_amdgcn_mfma_f32_16x16x32_bf16(aH, bQh, acc[0][mt], 0, 0, 0);
                acc[1][mt] = __builtin_amdgcn_mfma_f32_16x16x32_bf16(aL, bKh, acc[1][mt], 0, 0, 0);
                acc[1][mt] = __builtin_amdgcn_mfma_f32_16x16x32_bf16(aH, bKl, acc[1][mt], 0, 0, 0);
                acc[1][mt] = __builtin_amdgcn_mfma_f32_16x16x32_bf16(aH, bKh, acc[1][mt], 0, 0, 0);
                acc[2][mt] = __builtin_amdgcn_mfma_f32_16x16x32_bf16(aH, bVh, acc[2][mt], 0, 0, 0);
            }
        }
    }

    // write accumulators to sC (wave owns columns nt*16..nt*16+15)
    #pragma unroll
    for (int p = 0; p < 3; p++)
        #pragma unroll
        for (int mt = 0; mt < 4; mt++)
            #pragma unroll
            for (int r = 0; r < 4; r++)
                sC[p][mt * 16 + quad * 4 + r][nt * 16 + l15] = acc[p][mt][r];
    __syncthreads();

    const int b = r0 >> 11;
    const int gt0 = (r0 & 2047) >> 4;   // first 16-row tile index within batch

    // emit q,k packed hi/lo: wave handles m-subtile mtR = wid
    {
        const int mtR = wid;
        #pragma unroll
        for (int p = 0; p < 2; p++)
            #pragma unroll
            for (int ksR = 0; ksR < 2; ksR++) {
                const size_t dst = (size_t)b * NPB +
                    (((size_t)ksR * 128 + gt0 + mtR) * 64 + lane) * 8;
                const float* src = &sC[p][mtR * 16 + l15][ksR * 32 + quad * 8];
                f32x4 v0 = *(const f32x4*)src;
                f32x4 v1 = *(const f32x4*)(src + 4);
                bf16x8 h8, l8;
                #pragma unroll
                for (int j = 0; j < 4; j++) {
                    ushort_t h = f2bf(v0[j]);
                    h8[j] = (short)h;
                    l8[j] = (short)f2bf(v0[j] - bf2f(h));
                }
                #pragma unroll
                for (int j = 0; j < 4; j++) {
                    ushort_t h = f2bf(v1[j]);
                    h8[4 + j] = (short)h;
                    l8[4 + j] = (short)f2bf(v1[j] - bf2f(h));
                }
                *(bf16x8*)((p == 0 ? qpk : kpk) + dst) = h8;
                *(bf16x8*)((p == 0 ? qpl : kpl) + dst) = l8;
            }
    }
    // emit v packed (PV B-frag order, unscaled): wave = nt, 2 s-chunks
    // elem j = v[s = sc*32 + quad*8 + j][h = nt*16 + l15]
    {
        const int scL0 = (r0 & 2047) >> 5;       // first 32-row s-chunk
        #pragma unroll
        for (int sc = 0; sc < 2; sc++) {
            bf16x8 o;
            #pragma unroll
            for (int j = 0; j < 8; j++)
                o[j] = (short)f2bf(sC[2][sc * 32 + quad * 8 + j][nt * 16 + l15]);
            *(bf16x8*)(vpk + (size_t)b * NPB +
                       (((size_t)(scL0 + sc) * 4 + nt) * 64 + lane) * 8) = o;
        }
    }
}

// ---------------------------------------------------------------------------
// Kernel 2: l[b,s] += column sums of exp(qk^T); stores P = exp(S) bf16 in
// PV-A-fragment-packed triangular tiles. Block 128x128, wave 64x64.
// ---------------------------------------------------------------------------
__global__ __launch_bounds__(256) void colsum_mfma(
    const ushort_t* __restrict__ qpk, const ushort_t* __restrict__ qpl,
    const ushort_t* __restrict__ kpk, const ushort_t* __restrict__ kpl,
    float* __restrict__ lsum, ushort_t* __restrict__ Ppack)
{
    const int tc = blockIdx.x, st = blockIdx.y, b = blockIdx.z;
    if (tc < st) return;
    const int tid = threadIdx.x;
    const int lane = tid & 63, wid = tid >> 6;
    const int quad = lane >> 4, l15 = lane & 15;
    const int wy = wid >> 1, wx = wid & 1;
    const int t_base = tc * 128 + wy * 64;
    const int s_base = st * 128 + wx * 64;
    if (t_base < s_base) return;
    const bool needMask = (t_base == s_base);

    __shared__ __align__(16) ushort_t sT[4][64][72];   // 36.9 KB, wave-private

    const size_t bq = (size_t)b * NPB;
    const size_t lb8 = (size_t)lane * 8;

    // B preload: k fragments (packed layout = A layout)
    bf16x8 bH[4][2], bL[4][2];
    #pragma unroll
    for (int nt = 0; nt < 4; nt++)
        #pragma unroll
        for (int ks = 0; ks < 2; ks++) {
            const size_t off = bq + (((size_t)ks * 128 + (s_base >> 4) + nt) * 64) * 8 + lb8;
            bH[nt][ks] = *(const bf16x8*)(kpk + off);
            bL[nt][ks] = *(const bf16x8*)(kpl + off);
        }

    float cs[4] = {0.f, 0.f, 0.f, 0.f};

    #pragma unroll
    for (int mt = 0; mt < 4; mt++) {
        bf16x8 aH[2], aL[2];
        #pragma unroll
        for (int ks = 0; ks < 2; ks++) {
            const size_t off = bq + (((size_t)ks * 128 + (t_base >> 4) + mt) * 64) * 8 + lb8;
            aH[ks] = *(const bf16x8*)(qpk + off);
            aL[ks] = *(const bf16x8*)(qpl + off);
        }
        f32x4 acc[4];
        #pragma unroll
        for (int nt = 0; nt < 4; nt++)
            acc[nt] = (f32x4){0.f, 0.f, 0.f, 0.f};
        #pragma unroll
        for (int nt = 0; nt < 4; nt++)
            #pragma unroll
            for (int ks = 0; ks < 2; ks++) {
                acc[nt] = __builtin_amdgcn_mfma_f32_16x16x32_bf16(aL[ks], bH[nt][ks], acc[nt], 0, 0, 0);
                acc[nt] = __builtin_amdgcn_mfma_f32_16x16x32_bf16(aH[ks], bL[nt][ks], acc[nt], 0, 0, 0);
                acc[nt] = __builtin_amdgcn_mfma_f32_16x16x32_bf16(aH[ks], bH[nt][ks], acc[nt], 0, 0, 0);
            }
        #pragma unroll
        for (int nt = 0; nt < 4; nt++)
            #pragma unroll
            for (int r = 0; r < 4; r++) {
                float e = __expf(acc[nt][r]);
                if (needMask) {
                    int t = mt * 16 + quad * 4 + r;
                    int s = nt * 16 + l15;
                    if (t < s) e = 0.f;
                }
                cs[nt] += e;
                sT[wid][mt * 16 + quad * 4 + r][nt * 16 + l15] = f2bf(e);
            }
    }

    #pragma unroll
    for (int nt = 0; nt < 4; nt++) {
        float v = cs[nt];
        v += __shfl_xor(v, 16);
        v += __shfl_xor(v, 32);
        if (quad == 0)
            atomicAdd(lsum + (size_t)b * TT + s_base + nt * 16 + l15, v);
    }

    // emit P tile as 8 A-frag records: rec=(mtP,ksP), elem j = P[mtP*16+l15][ksP*32+quad*8+j]
    const int ti = t_base >> 6, si = s_base >> 6;
    ushort_t* tp = Ppack + ((size_t)b * NTRI + (size_t)(ti * (ti + 1) / 2) + si) * 4096;
    #pragma unroll
    for (int rec = 0; rec < 8; rec++) {
        const int mtP = rec >> 1, ksP = rec & 1;
        bf16x8 v8 = *(const bf16x8*)&sT[wid][mtP * 16 + l15][ksP * 32 + quad * 8];
        *(bf16x8*)(tp + (size_t)rec * 512 + lb8) = v8;
    }
}

// ---------------------------------------------------------------------------
// Kernel 2b: scale packed v records by 1/l[s]  (s = sc*32 + quad*8 + j)
// ---------------------------------------------------------------------------
__global__ __launch_bounds__(256) void vscale_kernel(
    const ushort_t* __restrict__ vpk, const float* __restrict__ lsum,
    ushort_t* __restrict__ vps)
{
    size_t slot = (size_t)blockIdx.x * 256 + threadIdx.x;   // 131072 slots
    int lane = (int)(slot & 63);
    int quad = lane >> 4;
    int sc_b = (int)(slot >> 8);          // b*64 + sc
    int b = sc_b >> 6, sc = sc_b & 63;
    bf16x8 in = *(const bf16x8*)(vpk + slot * 8);
    const float* lp = lsum + (size_t)b * TT + sc * 32 + quad * 8;
    float4 l0 = *(const float4*)lp;
    float4 l1 = *(const float4*)(lp + 4);
    float li[8] = {l0.x, l0.y, l0.z, l0.w, l1.x, l1.y, l1.z, l1.w};
    bf16x8 o;
    #pragma unroll
    for (int j = 0; j < 8; j++)
        o[j] = (short)f2bf(bf2f((ushort_t)in[j]) / li[j]);
    *(bf16x8*)(vps + slot * 8) = o;
}

// ---------------------------------------------------------------------------
// Kernel 3: out = P * vs^T from packed fragments. grid (32 pairs, 8 b).
// Block: t-tiles p and 63-p (32 rows each); 4 waves stride s-chunks.
// ---------------------------------------------------------------------------
__global__ __launch_bounds__(256) void attn_pv(
    const ushort_t* __restrict__ Ppack, const ushort_t* __restrict__ vps,
    float* __restrict__ out)
{
    const int p = blockIdx.x, b = blockIdx.y;
    const int tid = threadIdx.x;
    const int lane = tid & 63, wid = tid >> 6;
    const int quad = lane >> 4, l15 = lane & 15;
    const size_t lb8 = (size_t)lane * 8;

    __shared__ __align__(16) float red[4][2048];   // 32 KB

    const ushort_t* vb_ = vps + (size_t)b * NPB;

    #pragma unroll
    for (int half = 0; half < 2; half++) {
        const int tileI = half ? (63 - p) : p;
        const int t0 = tileI * 32;
        const int ti = t0 >> 6, trel16 = (t0 & 63) >> 4;   // 0 or 2
        const size_t triBase = ((size_t)b * NTRI + (size_t)(ti * (ti + 1) / 2)) * 4096;

        f32x4 oacc[2][4];
        #pragma unroll
        for (int mt = 0; mt < 2; mt++)
            #pragma unroll
            for (int nt = 0; nt < 4; nt++)
                oacc[mt][nt] = (f32x4){0.f, 0.f, 0.f, 0.f};

        for (int s0 = wid * 64; s0 <= t0 + 31; s0 += 256) {
            const int si = s0 >> 6;
            const ushort_t* tp = Ppack + triBase + (size_t)si * 4096;
            bf16x8 pa[2][2];
            #pragma unroll
            for (int mt = 0; mt < 2; mt++)
                #pragma unroll
                for (int ks = 0; ks < 2; ks++)
                    pa[mt][ks] = *(const bf16x8*)(tp + (size_t)((trel16 + mt) * 2 + ks) * 512 + lb8);
            #pragma unroll
            for (int ks = 0; ks < 2; ks++)
                #pragma unroll
                for (int nt = 0; nt < 4; nt++) {
                    bf16x8 vb = *(const bf16x8*)(vb_ + (((size_t)(s0 >> 5) + ks) * 4 + nt) * 512 + lb8);
                    #pragma unroll
                    for (int mt = 0; mt < 2; mt++)
                        oacc[mt][nt] = __builtin_amdgcn_mfma_f32_16x16x32_bf16(pa[mt][ks], vb, oacc[mt][nt], 0, 0, 0);
                }
        }

        __syncthreads();
        #pragma unroll
        for (int mt = 0; mt < 2; mt++)
            #pragma unroll
            for (int nt = 0; nt < 4; nt++)
                #pragma unroll
                for (int r = 0; r < 4; r++)
                    red[wid][(mt * 16 + quad * 4 + r) * 64 + nt * 16 + l15] =
                        oacc[mt][nt][r];
        __syncthreads();
        for (int e = tid; e < 2048; e += 256) {
            float s_ = red[0][e] + red[1][e] + red[2][e] + red[3][e];
            out[(size_t)(b * TT + t0 + (e >> 6)) * HH + (e & 63)] = s_;
        }
        __syncthreads();
    }
}

extern "C" void kernel_launch(void* const* d_in, const int* in_sizes, int n_in,
                              void* d_out, int out_size, void* d_ws, size_t ws_size,
                              hipStream_t stream)
{
    const float* x  = (const float*)d_in[0];
    const float* Wq = (const float*)d_in[1];
    const float* Wk = (const float*)d_in[2];
    const float* Wv = (const float*)d_in[3];
    float* out = (float*)d_out;

    const size_t N = (size_t)BB * TT * HH;     // 1,048,576
    ushort_t* qpk = (ushort_t*)d_ws;
    ushort_t* qpl = qpk + N;
    ushort_t* kpk = qpl + N;
    ushort_t* kpl = kpk + N;
    ushort_t* vpk = kpl + N;
    ushort_t* vps = vpk + N;
    float* lsum = (float*)(vps + N);                        // [8][2048]
    ushort_t* wpack = (ushort_t*)(lsum + (size_t)BB * TT);  // 327,680 elems
    ushort_t* Ppack = wpack + (size_t)5 * 32 * 4 * 512;     // 17,301,504 elems

    hipMemsetAsync(lsum, 0, (size_t)BB * TT * sizeof(float), stream);
    wsplit_kernel<<<dim3(160), 256, 0, stream>>>(Wq, Wk, Wv, wpack);
    proj_mfma<<<dim3(256), 256, 0, stream>>>(x, wpack, qpk, qpl, kpk, kpl, vpk);
    colsum_mfma<<<dim3(16, 16, BB), 256, 0, stream>>>(qpk, qpl, kpk, kpl, lsum, Ppack);
    vscale_kernel<<<dim3(512), 256, 0, stream>>>(vpk, lsum, vps);
    attn_pv<<<dim3(32, BB), 256, 0, stream>>>(Ppack, vps, out);
}